// Round 11
// baseline (1007.737 us; speedup 1.0000x reference)
//
#include <hip/hip_runtime.h>
#include <hip/hip_bf16.h>

typedef short bf16x8 __attribute__((ext_vector_type(8)));
typedef float f32x4 __attribute__((ext_vector_type(4)));
typedef unsigned short u16;
typedef unsigned int u32;

__device__ __forceinline__ u16 f2bf(float f) {
  unsigned u = __float_as_uint(f);
  u += 0x7FFFu + ((u >> 16) & 1u);
  return (u16)(u >> 16);
}

__device__ __forceinline__ void cp16(const u16* g, u16* l) {
  __builtin_amdgcn_global_load_lds((const __attribute__((address_space(1))) u32*)(const void*)g,
                                   (__attribute__((address_space(3))) u32*)(void*)l, 16, 0, 0);
}

// ---------------- prep: cast x to bf16 ----------------
__global__ void cast_x_kernel(const float4* __restrict__ x, ushort4* __restrict__ xb, int n4) {
  int stride = gridDim.x * blockDim.x;
  for (int i = blockIdx.x * blockDim.x + threadIdx.x; i < n4; i += stride) {
    float4 v = x[i];
    ushort4 o;
    o.x = f2bf(v.x); o.y = f2bf(v.y); o.z = f2bf(v.z); o.w = f2bf(v.w);
    xb[i] = o;
  }
}

// ---------------- prep: weights permute+cast ----------------
// qkv_w rows: o = h*96 + d*3 + t  (reference reshape (h,dh,3))
// permuted rows: o' = t*384 + h*32 + d
__global__ void prep_kernel(const float* __restrict__ qkv_w, const float* __restrict__ qkv_b,
                            const float* __restrict__ out_w,
                            u16* __restrict__ qkv_wp, float* __restrict__ qkv_bp,
                            u16* __restrict__ out_wb) {
  int stride = gridDim.x * blockDim.x;
  int tid0 = blockIdx.x * blockDim.x + threadIdx.x;
  for (int i = tid0; i < 1152 * 384; i += stride) {
    int op = i / 384, kk = i - op * 384;
    int t3 = op / 384, rem = op - t3 * 384;
    int h = rem >> 5, d = rem & 31;
    int o = h * 96 + d * 3 + t3;
    qkv_wp[i] = f2bf(qkv_w[o * 384 + kk]);
  }
  for (int i = tid0; i < 1152; i += stride) {
    int t3 = i / 384, rem = i - t3 * 384;
    int h = rem >> 5, d = rem & 31;
    qkv_bp[i] = qkv_b[h * 96 + d * 3 + t3];
  }
  for (int i = tid0; i < 384 * 384; i += stride) out_wb[i] = f2bf(out_w[i]);
}

// ---------------- precompute combined bias+mask: bm[w][h][49][64] f32, j-interleaved ----
// storage position j' = (j%16)*4 + j/16  -> lane lrow reads float4 {j=0*16+lrow..3*16+lrow}
// j in [49,64) = -1e30 (kills padded K columns in softmax, branch-free)
__global__ void bmask_kernel(const int* __restrict__ rp_index, const float* __restrict__ rp_table,
                             const float* __restrict__ mask, float* __restrict__ bm, int nW) {
  int id = blockIdx.x * blockDim.x + threadIdx.x;
  int total = nW * 12 * 49 * 64;
  if (id >= total) return;
  int jp = id & 63;
  int j = (jp & 3) * 16 + (jp >> 2);  // inverse of interleave
  int rest = id >> 6;                 // [w][h][i]
  int i = rest % 49;
  rest /= 49;
  int h = rest % 12;
  int w = rest / 12;
  float v;
  if (j < 49) {
    int ij = i * 49 + j;
    v = rp_table[rp_index[ij] * 12 + h] + mask[(size_t)w * 2401 + ij];
  } else {
    v = -1e30f;
  }
  bm[id] = v;
}

// ---------------- tall-skinny GEMM C = A @ B^T (+bias), BARRIER-FREE ----------------
// M huge, N in {1152, 384}, K=384. Block = 64 A-rows staged to LDS ONCE (48 KB, one
// barrier); B is L2-resident (<=0.88 MB) and read global->register per fragment. Waves
// split N 4 ways (self-paced, no further sync): chunks of 64/32 cols, full K per chunk.
// LDS XOR swizzle on A (store chunk (cs&~7)|((cs&7)^(row&7)) via pre-swizzled source;
// read chunk (c&~7)|((c&7)^(lrow&7))) -> <=2-way on ds_read_b128.
// MODE 1: N=1152; q -> outQ[12][M][32], k -> outK[12][M][32] (per-head planes),
//         v -> outVT[(b*12+h)*32+d][64], pad cols 49..63 zero-filled by n==48 thread.
// MODE 2: N=384; f32 epilogue (+bias) -> outF [M][384]
template <int MODE>
__global__ __launch_bounds__(256, 3) void gemm_tsk(const u16* __restrict__ A,
                                                   const u16* __restrict__ Bm,
                                                   const float* __restrict__ bias,
                                                   u16* __restrict__ outQ, u16* __restrict__ outK,
                                                   u16* __restrict__ outVT,
                                                   float* __restrict__ outF, int Mtot) {
  __shared__ u16 As[64 * 384];  // 48 KB
  int bid = blockIdx.x;
  size_t mBase = (size_t)bid * 64;
  int t = threadIdx.x, lane = t & 63, wid = t >> 6;
  int lrow = lane & 15, kg = lane >> 4;

  // stage A once: 12 chunks/thread, dest linear (gload_lds), source pre-swizzled
#pragma unroll
  for (int i = 0; i < 12; i++) {
    int ci = i * 256 + t;
    int row = ci / 48, cs = ci - row * 48;
    int csrc = (cs & ~7) | ((cs & 7) ^ (row & 7));
    cp16(A + (mBase + row) * 384 + csrc * 8, &As[ci * 8]);
  }
  __syncthreads();  // the ONLY barrier

#define DO_CHUNK(NT, CB)                                                                     \
  {                                                                                          \
    int colBase = (CB);                                                                      \
    f32x4 acc[4][NT] = {};                                                                   \
    _Pragma("unroll") for (int kk = 0; kk < 12; kk++) {                                      \
      bf16x8 af[4], bfr[NT];                                                                 \
      int c = kk * 4 + kg;                                                                   \
      int cz = (c & ~7) | ((c & 7) ^ (lrow & 7));                                            \
      _Pragma("unroll") for (int mt = 0; mt < 4; mt++)                                       \
          af[mt] = *(const bf16x8*)(&As[(mt * 16 + lrow) * 384 + cz * 8]);                   \
      _Pragma("unroll") for (int nt = 0; nt < NT; nt++)                                      \
          bfr[nt] = *(const bf16x8*)(Bm + (size_t)(colBase + nt * 16 + lrow) * 384 +         \
                                     kk * 32 + kg * 8);                                      \
      _Pragma("unroll") for (int mt = 0; mt < 4; mt++)                                       \
          _Pragma("unroll") for (int nt = 0; nt < NT; nt++) acc[mt][nt] =                    \
              __builtin_amdgcn_mfma_f32_16x16x32_bf16(af[mt], bfr[nt], acc[mt][nt], 0, 0, 0);\
    }                                                                                        \
    _Pragma("unroll") for (int nt = 0; nt < NT; nt++) {                                      \
      int col = colBase + nt * 16 + lrow;                                                    \
      float bv = bias[col];                                                                  \
      if (MODE == 1) {                                                                       \
        int t3 = col / 384;                                                                  \
        int rem = col - t3 * 384;                                                            \
        int hh = rem >> 5, dd = rem & 31;                                                    \
        _Pragma("unroll") for (int mt = 0; mt < 4; mt++)                                     \
            _Pragma("unroll") for (int r = 0; r < 4; r++) {                                  \
          int m = (int)mBase + mt * 16 + kg * 4 + r;                                         \
          u16 v = f2bf(acc[mt][nt][r] + bv);                                                 \
          if (t3 == 0) {                                                                     \
            outQ[((size_t)hh * Mtot + m) * 32 + dd] = v;                                     \
          } else if (t3 == 1) {                                                              \
            outK[((size_t)hh * Mtot + m) * 32 + dd] = v;                                     \
          } else {                                                                           \
            int b = m / 49, n = m - b * 49;                                                  \
            u16* vrow = &outVT[(((size_t)b * 12 + hh) * 32 + dd) * 64];                      \
            vrow[n] = v;                                                                     \
            if (n == 48) {                                                                   \
              _Pragma("unroll") for (int e = 49; e < 64; e++) vrow[e] = 0;                   \
            }                                                                                \
          }                                                                                  \
        }                                                                                    \
      } else {                                                                               \
        _Pragma("unroll") for (int mt = 0; mt < 4; mt++)                                     \
            _Pragma("unroll") for (int r = 0; r < 4; r++) {                                  \
          int m = (int)mBase + mt * 16 + kg * 4 + r;                                         \
          outF[(size_t)m * 384 + col] = acc[mt][nt][r] + bv;                                 \
        }                                                                                    \
      }                                                                                      \
    }                                                                                        \
  }

  if (MODE == 1) {
    int colBase0 = wid * 288;
    DO_CHUNK(4, colBase0);
    DO_CHUNK(4, colBase0 + 64);
    DO_CHUNK(4, colBase0 + 128);
    DO_CHUNK(4, colBase0 + 192);
    DO_CHUNK(2, colBase0 + 256);
  } else {
    int colBase0 = wid * 96;
    DO_CHUNK(4, colBase0);
    DO_CHUNK(2, colBase0 + 64);
  }
#undef DO_CHUNK
}

// ---------------- attention: 1 block per window, wave w -> heads w*3..w*3+2 ----------------
// Q/K from per-head planes [12][M][32] (3136B contiguous per (wave,head) -> full lines).
// Output staged in LDS, then ONE dense line-aligned coop store per block (49x768B).
__global__ __launch_bounds__(256, 4) void attn_kernel(const u16* __restrict__ qh,
                                                      const u16* __restrict__ kh,
                                                      const u16* __restrict__ vt,
                                                      const f32x4* __restrict__ bm,
                                                      u16* __restrict__ aout,
                                                      int M, int nW, int swz) {
  __shared__ u16 p_lds[4 * 4096];
  __shared__ u16 o_lds[49 * 400];  // row stride 400 u16 (800B)
  int bid = blockIdx.x;
  int b = bid;
  if (swz) {  // group blocks so each XCD sees only 8 distinct w=b%64 (bm L2-resident)
    int x = bid & 7, idx = bid >> 3;
    b = (idx >> 3) * 64 + x * 8 + (idx & 7);
  }
  int t = threadIdx.x, lane = t & 63, wid = t >> 6;
  int lrow = lane & 15, kg = lane >> 4;
  u16* pw = p_lds + wid * 4096;
  const float scale = 0.17677669529663687f;  // 32^-0.5
  int w = b % nW;
  int h0 = wid * 3;

  int nclamp[4];
#pragma unroll
  for (int mt = 0; mt < 4; mt++) {
    int n = mt * 16 + lrow;
    nclamp[mt] = (n < 49) ? n : 0;  // clamp pad rows to row 0: finite values, killed by bm
  }

  bf16x8 qf[2][4], kf[2][4];
#pragma unroll
  for (int mt = 0; mt < 4; mt++) {
    size_t off = ((size_t)h0 * M + b * 49 + nclamp[mt]) * 32 + kg * 8;
    qf[0][mt] = *(const bf16x8*)(qh + off);
    kf[0][mt] = *(const bf16x8*)(kh + off);
  }

#pragma unroll
  for (int hi = 0; hi < 3; hi++) {
    int h = h0 + hi;
    int cur = hi & 1;
    if (hi < 2) {  // prefetch next head's Q/K (independent of current compute)
      int nx = cur ^ 1;
#pragma unroll
      for (int mt = 0; mt < 4; mt++) {
        size_t off = ((size_t)(h + 1) * M + b * 49 + nclamp[mt]) * 32 + kg * 8;
        qf[nx][mt] = *(const bf16x8*)(qh + off);
        kf[nx][mt] = *(const bf16x8*)(kh + off);
      }
    }
    // prefetch V fragments: independent of softmax, HBM latency hides under VALU.
    // vt pad cols j=49..63 are zero-filled by gemm1 every call -> no masking needed.
    bf16x8 vv[2][2];
#pragma unroll
    for (int kt = 0; kt < 2; kt++)
#pragma unroll
      for (int nt = 0; nt < 2; nt++) {
        int d = nt * 16 + lrow;
        vv[kt][nt] =
            *(const bf16x8*)(vt + (((size_t)b * 12 + h) * 32 + d) * 64 + kt * 32 + kg * 8);
      }
    const f32x4* bmh4 = bm + ((size_t)w * 12 + h) * (49 * 16);
    // per-mt: QK mfma -> softmax -> P write (s live range = 16 VGPR)
#pragma unroll
    for (int mt = 0; mt < 4; mt++) {
      f32x4 s[4];
#pragma unroll
      for (int nt = 0; nt < 4; nt++) {
        f32x4 z = {0.f, 0.f, 0.f, 0.f};
        s[nt] = __builtin_amdgcn_mfma_f32_16x16x32_bf16(qf[cur][mt], kf[cur][nt], z, 0, 0, 0);
      }
#pragma unroll
      for (int r = 0; r < 4; r++) {
        int i = mt * 16 + kg * 4 + r;
        int irow = (i < 49) ? i : 48;  // rows i>=49 discarded; any finite bm row works
        f32x4 bv = bmh4[irow * 16 + lrow];
        float vals[4];
        float mx = -1e30f;
#pragma unroll
        for (int nt = 0; nt < 4; nt++) {
          float v = fmaf(s[nt][r], scale, bv[nt]);
          vals[nt] = v;
          mx = fmaxf(mx, v);
        }
#pragma unroll
        for (int off = 1; off < 16; off <<= 1) mx = fmaxf(mx, __shfl_xor(mx, off, 64));
        float sum = 0.f;
#pragma unroll
        for (int nt = 0; nt < 4; nt++) {
          float p = __expf(vals[nt] - mx);
          vals[nt] = p;
          sum += p;
        }
#pragma unroll
        for (int off = 1; off < 16; off <<= 1) sum += __shfl_xor(sum, off, 64);
        float inv = 1.0f / sum;
#pragma unroll
        for (int nt = 0; nt < 4; nt++) {
          int j = nt * 16 + lrow;
          int addr = ((i * 64 + j) * 2) ^ ((i & 7) << 4);
          *(u16*)((char*)pw + addr) = f2bf(vals[nt] * inv);
        }
      }
    }
    asm volatile("s_waitcnt lgkmcnt(0)" ::: "memory");
    // PV: O[i][d] = sum_j P[i][j] * V[j][d]
    f32x4 o[4][2];
#pragma unroll
    for (int mt = 0; mt < 4; mt++)
#pragma unroll
      for (int nt = 0; nt < 2; nt++) o[mt][nt] = (f32x4){0.f, 0.f, 0.f, 0.f};
#pragma unroll
    for (int kt = 0; kt < 2; kt++) {
      bf16x8 pf[4];
#pragma unroll
      for (int mt = 0; mt < 4; mt++) {
        int i = mt * 16 + lrow;
        int j = kt * 32 + kg * 8;
        int addr = ((i * 64 + j) * 2) ^ ((i & 7) << 4);
        pf[mt] = *(const bf16x8*)((const char*)pw + addr);
      }
#pragma unroll
      for (int mt = 0; mt < 4; mt++)
#pragma unroll
        for (int nt = 0; nt < 2; nt++)
          o[mt][nt] = __builtin_amdgcn_mfma_f32_16x16x32_bf16(pf[mt], vv[kt][nt], o[mt][nt], 0, 0, 0);
    }
    // stage o_h into LDS (wave-disjoint columns h*32..h*32+31)
#pragma unroll
    for (int mt = 0; mt < 4; mt++)
#pragma unroll
      for (int nt = 0; nt < 2; nt++)
#pragma unroll
        for (int r = 0; r < 4; r++) {
          int i = mt * 16 + kg * 4 + r;
          if (i < 49) {
            int d = nt * 16 + lrow;
            o_lds[i * 400 + h * 32 + d] = f2bf(o[mt][nt][r]);
          }
        }
  }
  __syncthreads();
  // dense line-aligned cooperative store: 49*384 u16 = 37632B = 294 full 128B lines
  u16* ab = aout + (size_t)b * 49 * 384;
  for (int idx = t; idx < 49 * 48; idx += 256) {
    int row = idx / 48, c = idx - row * 48;
    *(bf16x8*)(ab + row * 384 + c * 8) = *(const bf16x8*)(&o_lds[row * 400 + c * 8]);
  }
}

extern "C" void kernel_launch(void* const* d_in, const int* in_sizes, int n_in,
                              void* d_out, int out_size, void* d_ws, size_t ws_size,
                              hipStream_t stream) {
  const float* x = (const float*)d_in[0];
  const float* qkv_w = (const float*)d_in[1];
  const float* qkv_b = (const float*)d_in[2];
  const float* rp_table = (const float*)d_in[3];
  const float* out_w = (const float*)d_in[4];
  const float* out_b = (const float*)d_in[5];
  const int* rp_index = (const int*)d_in[6];
  const float* mask = (const float*)d_in[7];

  int Bwin = in_sizes[0] / (49 * 384);  // 4096
  int nW = in_sizes[7] / (49 * 49);     // 64
  int M = Bwin * 49;                    // 200704 (divisible by 64)

  char* ws = (char*)d_ws;
  u16* xb = (u16*)(ws);                      // 154,140,672 B (also reused as attn_out)
  u16* qhbuf = (u16*)(ws + 154140672);       // 154,140,672 B : [12][M][32] bf16
  u16* khbuf = (u16*)(ws + 308281344);       // 154,140,672 B : [12][M][32] bf16
  u16* vtbuf = (u16*)(ws + 462422016);       // 201,326,592 B : [B*12*32][64] bf16
  u16* qkv_wp = (u16*)(ws + 663748608);      // 884,736 B
  float* qkv_bp = (float*)(ws + 664633344);  // 4,608 B
  u16* out_wb = (u16*)(ws + 664637952);      // 294,912 B
  float* bmbuf = (float*)(ws + 664932864);   // nW*12*49*64*4 = 9,633,792 B
  u16* attn_out = xb;                        // alias: xb dead after gemm1; layout [M][384]

  int n4 = in_sizes[0] / 4;
  cast_x_kernel<<<4096, 256, 0, stream>>>((const float4*)x, (ushort4*)xb, n4);
  prep_kernel<<<1184, 256, 0, stream>>>(qkv_w, qkv_b, out_w, qkv_wp, qkv_bp, out_wb);
  int bmtotal = nW * 12 * 49 * 64;
  bmask_kernel<<<(bmtotal + 255) / 256, 256, 0, stream>>>(rp_index, rp_table, mask, bmbuf, nW);
  gemm_tsk<1><<<M / 64, 256, 0, stream>>>(xb, qkv_wp, qkv_bp, qhbuf, khbuf, vtbuf, nullptr, M);
  int swz = (nW == 64 && (Bwin & 63) == 0) ? 1 : 0;
  attn_kernel<<<Bwin, 256, 0, stream>>>(qhbuf, khbuf, vtbuf, (const f32x4*)bmbuf, attn_out, M, nW, swz);
  gemm_tsk<2><<<M / 64, 256, 0, stream>>>(attn_out, out_wb, out_b, nullptr, nullptr, nullptr,
                                          (float*)d_out, M);
}

// Round 12
// 901.438 us; speedup vs baseline: 1.1179x; 1.1179x over previous
//
#include <hip/hip_runtime.h>
#include <hip/hip_bf16.h>

typedef short bf16x8 __attribute__((ext_vector_type(8)));
typedef float f32x4 __attribute__((ext_vector_type(4)));
typedef unsigned short u16;
typedef unsigned int u32;

__device__ __forceinline__ u16 f2bf(float f) {
  unsigned u = __float_as_uint(f);
  u += 0x7FFFu + ((u >> 16) & 1u);
  return (u16)(u >> 16);
}

__device__ __forceinline__ void cp16(const u16* g, u16* l) {
  __builtin_amdgcn_global_load_lds((const __attribute__((address_space(1))) u32*)(const void*)g,
                                   (__attribute__((address_space(3))) u32*)(void*)l, 16, 0, 0);
}

// ---------------- prep: cast x to bf16 ----------------
__global__ void cast_x_kernel(const float4* __restrict__ x, ushort4* __restrict__ xb, int n4) {
  int stride = gridDim.x * blockDim.x;
  for (int i = blockIdx.x * blockDim.x + threadIdx.x; i < n4; i += stride) {
    float4 v = x[i];
    ushort4 o;
    o.x = f2bf(v.x); o.y = f2bf(v.y); o.z = f2bf(v.z); o.w = f2bf(v.w);
    xb[i] = o;
  }
}

// ---------------- prep: weights permute+cast ----------------
// qkv_w rows: o = h*96 + d*3 + t  (reference reshape (h,dh,3))
// permuted rows: o' = t*384 + h*32 + d
__global__ void prep_kernel(const float* __restrict__ qkv_w, const float* __restrict__ qkv_b,
                            const float* __restrict__ out_w,
                            u16* __restrict__ qkv_wp, float* __restrict__ qkv_bp,
                            u16* __restrict__ out_wb) {
  int stride = gridDim.x * blockDim.x;
  int tid0 = blockIdx.x * blockDim.x + threadIdx.x;
  for (int i = tid0; i < 1152 * 384; i += stride) {
    int op = i / 384, kk = i - op * 384;
    int t3 = op / 384, rem = op - t3 * 384;
    int h = rem >> 5, d = rem & 31;
    int o = h * 96 + d * 3 + t3;
    qkv_wp[i] = f2bf(qkv_w[o * 384 + kk]);
  }
  for (int i = tid0; i < 1152; i += stride) {
    int t3 = i / 384, rem = i - t3 * 384;
    int h = rem >> 5, d = rem & 31;
    qkv_bp[i] = qkv_b[h * 96 + d * 3 + t3];
  }
  for (int i = tid0; i < 384 * 384; i += stride) out_wb[i] = f2bf(out_w[i]);
}

// ---------------- precompute combined bias+mask: bm[w][h][49][64] f32, j-interleaved ----
// storage position j' = (j%16)*4 + j/16  -> lane lrow reads float4 {j=0*16+lrow..3*16+lrow}
// j in [49,64) = -1e30 (kills padded K columns in softmax, branch-free)
__global__ void bmask_kernel(const int* __restrict__ rp_index, const float* __restrict__ rp_table,
                             const float* __restrict__ mask, float* __restrict__ bm, int nW) {
  int id = blockIdx.x * blockDim.x + threadIdx.x;
  int total = nW * 12 * 49 * 64;
  if (id >= total) return;
  int jp = id & 63;
  int j = (jp & 3) * 16 + (jp >> 2);  // inverse of interleave
  int rest = id >> 6;                 // [w][h][i]
  int i = rest % 49;
  rest /= 49;
  int h = rest % 12;
  int w = rest / 12;
  float v;
  if (j < 49) {
    int ij = i * 49 + j;
    v = rp_table[rp_index[ij] * 12 + h] + mask[(size_t)w * 2401 + ij];
  } else {
    v = -1e30f;
  }
  bm[id] = v;
}

// ---------------- GEMM C = A @ B^T (+bias), 128x128 tile, BK=64 ----------------
// R9 loop (best measured): single-buffer 32 KB LDS, (256,4) -> 4 blocks/CU.
// T2 XOR swizzle + T1 bijective XCD swizzle.
// MODE 1: DENSE bf16 epilogue -> outQK[M][1152] (every 128B line fully written by one
//         block: zero write amplification; V transpose moved into attn).
// MODE 2: f32 epilogue (+bias) -> outF [M][384]
template <int MODE>
__global__ __launch_bounds__(256, 4) void gemm_bt(const u16* __restrict__ A, const u16* __restrict__ Bm,
                                                  const float* __restrict__ bias,
                                                  u16* __restrict__ outQK,
                                                  float* __restrict__ outF, int K, int ntiles) {
  __shared__ u16 As[128 * 64], Bs[128 * 64];
  int nwg = gridDim.x;
  int bid0 = blockIdx.x;
  int bid = ((nwg & 7) == 0) ? ((bid0 & 7) * (nwg >> 3) + (bid0 >> 3)) : bid0;
  int bm = bid / ntiles, bn = bid - bm * ntiles;
  size_t mBase = (size_t)bm * 128;
  int nBase = bn * 128;
  int Ncols = ntiles * 128;
  int t = threadIdx.x, lane = t & 63, wid = t >> 6;
  int wm = (wid >> 1) * 64, wn = (wid & 1) * 64;
  int lrow = lane & 15, kg = lane >> 4;
  int srow = t >> 3;              // staging row within 32-row group
  int sc = (t & 7) ^ (srow & 7);  // pre-swizzled source chunk (16B units, 0..7)
  f32x4 acc[4][4] = {};

  const u16* Arow = A + mBase * K;
  const u16* Brow = Bm + (size_t)nBase * K;

  int nk = K / 64;
  for (int tk = 0; tk < nk; ++tk) {
    __syncthreads();  // previous iteration's LDS reads complete before overwrite
#pragma unroll
    for (int i = 0; i < 4; i++) {
      int row = srow + 32 * i;
      cp16(Arow + (size_t)row * K + tk * 64 + sc * 8, &As[(t + 256 * i) * 8]);
      cp16(Brow + (size_t)row * K + tk * 64 + sc * 8, &Bs[(t + 256 * i) * 8]);
    }
    __syncthreads();  // stage landed (vmcnt drained by barrier semantics)
#pragma unroll
    for (int kk = 0; kk < 2; kk++) {
      bf16x8 af[4], bfr[4];
      int ck = ((kk << 2) | kg) ^ (lrow & 7);
#pragma unroll
      for (int mt = 0; mt < 4; mt++)
        af[mt] = *(const bf16x8*)(&As[(wm + mt * 16 + lrow) * 64 + ck * 8]);
#pragma unroll
      for (int nt = 0; nt < 4; nt++)
        bfr[nt] = *(const bf16x8*)(&Bs[(wn + nt * 16 + lrow) * 64 + ck * 8]);
#pragma unroll
      for (int mt = 0; mt < 4; mt++)
#pragma unroll
        for (int nt = 0; nt < 4; nt++)
          acc[mt][nt] = __builtin_amdgcn_mfma_f32_16x16x32_bf16(af[mt], bfr[nt], acc[mt][nt], 0, 0, 0);
    }
  }

#pragma unroll
  for (int mt = 0; mt < 4; mt++) {
#pragma unroll
    for (int nt = 0; nt < 4; nt++) {
      int col = nBase + wn + nt * 16 + lrow;
      float bv = bias[col];
#pragma unroll
      for (int r = 0; r < 4; r++) {
        int m = (int)mBase + wm + mt * 16 + kg * 4 + r;
        if (MODE == 1) {
          outQK[(size_t)m * Ncols + col] = f2bf(acc[mt][nt][r] + bv);
        } else {
          outF[(size_t)m * Ncols + col] = acc[mt][nt][r] + bv;
        }
      }
    }
  }
}

// ---------------- attention: 1 block per window, wave w -> heads w*3..w*3+2 ----------------
// qkv dense [M][1152]: q at h*32, k at 384+h*32, v at 768+h*32 (all L2/L3-resident reads).
// V^T built per wave per head in LDS (4KB) via u16 scatter with two-term XOR swizzle
// (write & read both ~2 lanes/bank per 16-lane phase). Output staged in o_lds, then ONE
// dense line-aligned coop store per block (49x768B) -> no partial-line writes.
__global__ __launch_bounds__(256, 4) void attn_kernel(const u16* __restrict__ qkv,
                                                      const f32x4* __restrict__ bm,
                                                      u16* __restrict__ aout,
                                                      int nW, int swz) {
  __shared__ u16 p_lds[4 * 4096];
  __shared__ u16 vt_lds[4 * 2048];  // per wave [32 d][64 j] swizzled
  __shared__ u16 o_lds[49 * 400];   // row stride 400 u16 (800B)
  int bid = blockIdx.x;
  int b = bid;
  if (swz) {  // group blocks so each XCD sees only 8 distinct w=b%64 (bm L2-resident)
    int x = bid & 7, idx = bid >> 3;
    b = (idx >> 3) * 64 + x * 8 + (idx & 7);
  }
  int t = threadIdx.x, lane = t & 63, wid = t >> 6;
  int lrow = lane & 15, kg = lane >> 4;
  u16* pw = p_lds + wid * 4096;
  u16* vw = vt_lds + wid * 2048;
  const float scale = 0.17677669529663687f;  // 32^-0.5
  int w = b % nW;
  int h0 = wid * 3;
  bf16x8 zer = {0, 0, 0, 0, 0, 0, 0, 0};

  int nclamp[4];
#pragma unroll
  for (int mt = 0; mt < 4; mt++) {
    int n = mt * 16 + lrow;
    nclamp[mt] = (n < 49) ? n : 0;  // clamp pad rows to row 0: finite values, killed by bm
  }

  bf16x8 qf[2][4], kf[2][4];
#pragma unroll
  for (int mt = 0; mt < 4; mt++) {
    const u16* base = qkv + (size_t)(b * 49 + nclamp[mt]) * 1152 + h0 * 32 + kg * 8;
    qf[0][mt] = *(const bf16x8*)base;
    kf[0][mt] = *(const bf16x8*)(base + 384);
  }

#pragma unroll
  for (int hi = 0; hi < 3; hi++) {
    int h = h0 + hi;
    int cur = hi & 1;
    if (hi < 2) {  // prefetch next head's Q/K (independent of current compute)
      int nx = cur ^ 1;
#pragma unroll
      for (int mt = 0; mt < 4; mt++) {
        const u16* base = qkv + (size_t)(b * 49 + nclamp[mt]) * 1152 + (h + 1) * 32 + kg * 8;
        qf[nx][mt] = *(const bf16x8*)base;
        kf[nx][mt] = *(const bf16x8*)(base + 384);
      }
    }
    // issue V reads early (64B-chunked, coalesced); latency hides under softmax VALU
    bf16x8 vreg[4];
#pragma unroll
    for (int c = 0; c < 4; c++) {
      int idx = c * 64 + lane;
      int j = idx >> 2, dc = idx & 3;
      vreg[c] = (j < 49)
                    ? *(const bf16x8*)(qkv + (size_t)(b * 49 + j) * 1152 + 768 + h * 32 + dc * 8)
                    : zer;
    }
    const f32x4* bmh4 = bm + ((size_t)w * 12 + h) * (49 * 16);
    // per-mt: QK mfma -> softmax -> P write (s live range = 16 VGPR)
#pragma unroll
    for (int mt = 0; mt < 4; mt++) {
      f32x4 s[4];
#pragma unroll
      for (int nt = 0; nt < 4; nt++) {
        f32x4 z = {0.f, 0.f, 0.f, 0.f};
        s[nt] = __builtin_amdgcn_mfma_f32_16x16x32_bf16(qf[cur][mt], kf[cur][nt], z, 0, 0, 0);
      }
#pragma unroll
      for (int r = 0; r < 4; r++) {
        int i = mt * 16 + kg * 4 + r;
        int irow = (i < 49) ? i : 48;  // rows i>=49 discarded; any finite bm row works
        f32x4 bv = bmh4[irow * 16 + lrow];
        float vals[4];
        float mx = -1e30f;
#pragma unroll
        for (int nt = 0; nt < 4; nt++) {
          float v = fmaf(s[nt][r], scale, bv[nt]);
          vals[nt] = v;
          mx = fmaxf(mx, v);
        }
#pragma unroll
        for (int off = 1; off < 16; off <<= 1) mx = fmaxf(mx, __shfl_xor(mx, off, 64));
        float sum = 0.f;
#pragma unroll
        for (int nt = 0; nt < 4; nt++) {
          float p = __expf(vals[nt] - mx);
          vals[nt] = p;
          sum += p;
        }
#pragma unroll
        for (int off = 1; off < 16; off <<= 1) sum += __shfl_xor(sum, off, 64);
        float inv = 1.0f / sum;
#pragma unroll
        for (int nt = 0; nt < 4; nt++) {
          int j = nt * 16 + lrow;
          int addr = ((i * 64 + j) * 2) ^ ((i & 7) << 4);
          *(u16*)((char*)pw + addr) = f2bf(vals[nt] * inv);
        }
      }
    }
    // scatter V^T into vt_lds: element v[j][d] at byte (d*128 + j*2) ^ ((d&7)<<4) ^ (((d>>3)&3)<<5)
#pragma unroll
    for (int c = 0; c < 4; c++) {
      int idx = c * 64 + lane;
      int j = idx >> 2, dc = idx & 3;
#pragma unroll
      for (int e = 0; e < 8; e++) {
        int ba = ((dc * 8 + e) * 128 + j * 2) ^ (e << 4) ^ (dc << 5);
        *(u16*)((char*)vw + ba) = (u16)vreg[c][e];  // zer for j>=49 (0*NaN guard)
      }
    }
    asm volatile("s_waitcnt lgkmcnt(0)" ::: "memory");
    // PV: O[i][d] = sum_j P[i][j] * V[j][d]
    f32x4 o[4][2];
#pragma unroll
    for (int mt = 0; mt < 4; mt++)
#pragma unroll
      for (int nt = 0; nt < 2; nt++) o[mt][nt] = (f32x4){0.f, 0.f, 0.f, 0.f};
#pragma unroll
    for (int kt = 0; kt < 2; kt++) {
      bf16x8 pf[4], vv[2];
#pragma unroll
      for (int mt = 0; mt < 4; mt++) {
        int i = mt * 16 + lrow;
        int j = kt * 32 + kg * 8;
        int addr = ((i * 64 + j) * 2) ^ ((i & 7) << 4);
        pf[mt] = *(const bf16x8*)((const char*)pw + addr);
      }
#pragma unroll
      for (int nt = 0; nt < 2; nt++) {
        int d = nt * 16 + lrow;
        int ba = (d * 128 + (kt * 32 + kg * 8) * 2) ^ ((d & 7) << 4) ^ (((d >> 3) & 3) << 5);
        vv[nt] = *(const bf16x8*)((const char*)vw + ba);
      }
#pragma unroll
      for (int mt = 0; mt < 4; mt++)
#pragma unroll
        for (int nt = 0; nt < 2; nt++)
          o[mt][nt] = __builtin_amdgcn_mfma_f32_16x16x32_bf16(pf[mt], vv[nt], o[mt][nt], 0, 0, 0);
    }
    // stage o_h into LDS (wave-disjoint columns h*32..h*32+31)
#pragma unroll
    for (int mt = 0; mt < 4; mt++)
#pragma unroll
      for (int nt = 0; nt < 2; nt++)
#pragma unroll
        for (int r = 0; r < 4; r++) {
          int i = mt * 16 + kg * 4 + r;
          if (i < 49) {
            int d = nt * 16 + lrow;
            o_lds[i * 400 + h * 32 + d] = f2bf(o[mt][nt][r]);
          }
        }
  }
  __syncthreads();
  // dense line-aligned cooperative store: 49*384 u16 = 37632B = 294 full 128B lines
  u16* ab = aout + (size_t)b * 49 * 384;
  for (int idx = t; idx < 49 * 48; idx += 256) {
    int row = idx / 48, c = idx - row * 48;
    *(bf16x8*)(ab + row * 384 + c * 8) = *(const bf16x8*)(&o_lds[row * 400 + c * 8]);
  }
}

extern "C" void kernel_launch(void* const* d_in, const int* in_sizes, int n_in,
                              void* d_out, int out_size, void* d_ws, size_t ws_size,
                              hipStream_t stream) {
  const float* x = (const float*)d_in[0];
  const float* qkv_w = (const float*)d_in[1];
  const float* qkv_b = (const float*)d_in[2];
  const float* rp_table = (const float*)d_in[3];
  const float* out_w = (const float*)d_in[4];
  const float* out_b = (const float*)d_in[5];
  const int* rp_index = (const int*)d_in[6];
  const float* mask = (const float*)d_in[7];

  int Bwin = in_sizes[0] / (49 * 384);  // 4096
  int nW = in_sizes[7] / (49 * 49);     // 64
  int M = Bwin * 49;                    // 200704 (divisible by 128)

  char* ws = (char*)d_ws;
  u16* xb = (u16*)(ws);                      // 154,140,672 B (reused as attn_out)
  u16* qkvbuf = (u16*)(ws + 154140672);      // 462,422,016 B : [M][1152] bf16 dense
  u16* qkv_wp = (u16*)(ws + 616562688);      // 884,736 B
  float* qkv_bp = (float*)(ws + 617447424);  // 4,608 B
  u16* out_wb = (u16*)(ws + 617452032);      // 294,912 B
  float* bmbuf = (float*)(ws + 617746944);   // nW*12*49*64*4 = 9,633,792 B
  u16* attn_out = xb;                        // alias: xb dead after gemm1; layout [M][384]

  int n4 = in_sizes[0] / 4;
  cast_x_kernel<<<4096, 256, 0, stream>>>((const float4*)x, (ushort4*)xb, n4);
  prep_kernel<<<1184, 256, 0, stream>>>(qkv_w, qkv_b, out_w, qkv_wp, qkv_bp, out_wb);
  int bmtotal = nW * 12 * 49 * 64;
  bmask_kernel<<<(bmtotal + 255) / 256, 256, 0, stream>>>(rp_index, rp_table, mask, bmbuf, nW);
  gemm_bt<1><<<(M / 128) * 9, 256, 0, stream>>>(xb, qkv_wp, qkv_bp, qkvbuf, nullptr, 384, 9);
  int swz = (nW == 64 && (Bwin & 63) == 0) ? 1 : 0;
  attn_kernel<<<Bwin, 256, 0, stream>>>(qkvbuf, (const f32x4*)bmbuf, attn_out, nW, swz);
  gemm_bt<2><<<(M / 128) * 3, 256, 0, stream>>>(attn_out, out_wb, out_b, nullptr,
                                                (float*)d_out, 384, 3);
}